// Round 5
// baseline (493.390 us; speedup 1.0000x reference)
//
#include <hip/hip_runtime.h>
#include <math.h>

#define TPC 225
#define NCLS 224
#define NHID 1024
#define BATCH 2048
#define CAP 256      // bucket capacity per class (mean ~9.1)
#define LSTRIDE 256  // logits ws row stride (floats)

// ---------------------------------------------------------------------------
// Kernel 1: bucket examples by class. Single block, LDS atomics.
// ---------------------------------------------------------------------------
__global__ __launch_bounds__(256) void hs_bucket(const int* __restrict__ labels,
                                                 int* __restrict__ bucket,
                                                 int* __restrict__ cnt) {
    __shared__ int scnt[NCLS];
    const int t = threadIdx.x;
    for (int i = t; i < NCLS; i += 256) scnt[i] = 0;
    __syncthreads();
    for (int b = t; b < BATCH; b += 256) {
        int lab = labels[b];
        int c = lab / TPC;
        int pos = atomicAdd(&scnt[c], 1);
        bucket[c * CAP + pos] = b;
    }
    __syncthreads();
    for (int i = t; i < NCLS; i += 256) cnt[i] = scnt[i];
}

// ---------------------------------------------------------------------------
// Kernel 2: top logits. 256 blocks x 1024 thr; block owns 8 rows (staged in
// LDS). 16 waves = 4 k-chunks x 4 d-quarters; each wave computes all 8 rows
// against its PRIVATE W slice (no duplicate W reads). W_top L2-resident.
// Cross-d reduction in LDS -> tws[row*LSTRIDE+col].
// ---------------------------------------------------------------------------
__global__ __launch_bounds__(1024, 4) void hs_tlogits(const float* __restrict__ x,
                                                      const float* __restrict__ W,
                                                      float* __restrict__ tws) {
    __shared__ float xs[8 * NHID];        // 32 KB staged rows
    __shared__ float red[4][8][256];      // 32 KB partials [wdq][row][k]
    const int t = threadIdx.x;
    const int r0 = blockIdx.x * 8;

    // stage 8 rows (coalesced float4)
#pragma unroll
    for (int i = 0; i < 2; i++) {
        int idx = i * 1024 + t;           // 0..2047 float4 slots
        int row = idx >> 8, col = idx & 255;
        ((float4*)xs)[idx] = ((const float4*)(x + (size_t)(r0 + row) * NHID))[col];
    }
    __syncthreads();

    const int lane = t & 63;
    const int wave = t >> 6;
    const int wk = wave & 3;              // k-chunk (64 cols)
    const int wdq = wave >> 2;            // d-quarter (256 d)
    const int k = min(wk * 64 + lane, NCLS - 1);
    const float* wp = W + (size_t)(wdq * 256) * NCLS + k;

    float acc[8] = {};
    float wcur[4];
#pragma unroll
    for (int di = 0; di < 4; di++) wcur[di] = wp[di * NCLS];
    wp += 4 * NCLS;
    for (int dq = 0; dq < 64; ++dq) {
        float wnxt[4];
        if (dq < 63) {
#pragma unroll
            for (int di = 0; di < 4; di++) wnxt[di] = wp[di * NCLS];
            wp += 4 * NCLS;
        }
        const float4* xq = (const float4*)xs + (wdq * 64 + dq);
#pragma unroll
        for (int rl = 0; rl < 8; ++rl) {
            float4 xv = xq[rl * 256];     // LDS broadcast read
#pragma unroll
            for (int di = 0; di < 4; di++)
                acc[rl] = fmaf(((const float*)&xv)[di], wcur[di], acc[rl]);
        }
#pragma unroll
        for (int di = 0; di < 4; di++) wcur[di] = wnxt[di];
    }
#pragma unroll
    for (int rl = 0; rl < 8; ++rl) red[wdq][rl][wk * 64 + lane] = acc[rl];
    __syncthreads();

    for (int i = t; i < 8 * 256; i += 1024) {
        int row = i >> 8, col = i & 255;
        if (col < NCLS) {
            float s = red[0][row][col] + red[1][row][col] +
                      red[2][row][col] + red[3][row][col];
            tws[(size_t)(r0 + row) * LSTRIDE + col] = s;
        }
    }
}

// ---------------------------------------------------------------------------
// Kernel 3: bottom logits. Grid = 224 classes x 4 sub-blocks of 16 rows
// (empties exit). 16 waves = 4 k-chunks x 4 d-quarters; each wave computes
// all 16 staged rows against its private W slice -> W read ONCE per class.
// ---------------------------------------------------------------------------
__global__ __launch_bounds__(1024, 4) void hs_blogits(const float* __restrict__ x,
                                                      const float* __restrict__ Wb,
                                                      const int* __restrict__ bucket,
                                                      const int* __restrict__ cnt,
                                                      float* __restrict__ bws) {
    __shared__ float xs[16 * NHID];       // 64 KB staged rows
    __shared__ float red[4][16][256];     // 64 KB partials
    __shared__ int srow[16];
    const int c = blockIdx.x >> 2;
    const int base = (blockIdx.x & 3) * 16;
    const int n = cnt[c];
    if (base >= n) return;
    const int m = min(n - base, 16);
    const int t = threadIdx.x;
    const int* bucket_c = bucket + c * CAP;

    if (t < 16) srow[t] = bucket_c[min(base + t, n - 1)];  // pad -> valid row
    __syncthreads();

    // stage 16 rows (coalesced float4)
#pragma unroll
    for (int i = 0; i < 4; i++) {
        int idx = i * 1024 + t;           // 0..4095 float4 slots
        int row = idx >> 8, col = idx & 255;
        ((float4*)xs)[idx] = ((const float4*)(x + (size_t)srow[row] * NHID))[col];
    }
    __syncthreads();

    const int lane = t & 63;
    const int wave = t >> 6;
    const int wk = wave & 3;
    const int wdq = wave >> 2;
    const int k = min(wk * 64 + lane, TPC - 1);
    const float* wp = Wb + (size_t)c * (NHID * TPC) + (size_t)(wdq * 256) * TPC + k;

    float acc[16] = {};
    float wcur[4];
#pragma unroll
    for (int di = 0; di < 4; di++) wcur[di] = wp[di * TPC];
    wp += 4 * TPC;
    for (int dq = 0; dq < 64; ++dq) {
        float wnxt[4];
        if (dq < 63) {
#pragma unroll
            for (int di = 0; di < 4; di++) wnxt[di] = wp[di * TPC];
            wp += 4 * TPC;
        }
        const float4* xq = (const float4*)xs + (wdq * 64 + dq);
#pragma unroll
        for (int rl = 0; rl < 16; ++rl) {
            float4 xv = xq[rl * 256];     // LDS broadcast read
#pragma unroll
            for (int di = 0; di < 4; di++)
                acc[rl] = fmaf(((const float*)&xv)[di], wcur[di], acc[rl]);
        }
#pragma unroll
        for (int di = 0; di < 4; di++) wcur[di] = wnxt[di];
    }
#pragma unroll
    for (int rl = 0; rl < 16; ++rl) red[wdq][rl][wk * 64 + lane] = acc[rl];
    __syncthreads();

    for (int i = t; i < m * 256; i += 1024) {
        int row = i >> 8, col = i & 255;
        if (col < TPC) {
            float s = red[0][row][col] + red[1][row][col] +
                      red[2][row][col] + red[3][row][col];
            bws[(size_t)srow[row] * LSTRIDE + col] = s;
        }
    }
}

// ---------------------------------------------------------------------------
// Kernel 4: finish. One wave per row: softmax over top (224) and bottom (225)
// logits (bias added here), pick cls/word, out[row] = p_cls * p_word.
// ---------------------------------------------------------------------------
__global__ __launch_bounds__(256) void hs_finish(const float* __restrict__ tws,
                                                 const float* __restrict__ bws,
                                                 const int* __restrict__ labels,
                                                 const float* __restrict__ b_top,
                                                 const float* __restrict__ b_bot,
                                                 float* __restrict__ out) {
    const int lane = threadIdx.x & 63;
    const int wave = threadIdx.x >> 6;
    const int row = blockIdx.x * 4 + wave;
    const int label = labels[row];
    const int c = label / TPC;
    const int word = label - c * TPC;

    float p[2];
#pragma unroll
    for (int lvl = 0; lvl < 2; lvl++) {
        const int NS = lvl ? TPC : NCLS;
        const int pick = lvl ? word : c;
        const float* lws = lvl ? bws : tws;
        const float* bias = lvl ? (b_bot + c * TPC) : b_top;
        float lg[4];
#pragma unroll
        for (int j = 0; j < 4; j++) {
            int k = lane + 64 * j;
            lg[j] = (k < NS) ? lws[(size_t)row * LSTRIDE + k] + bias[k] : -INFINITY;
        }
        float m = fmaxf(fmaxf(lg[0], lg[1]), fmaxf(lg[2], lg[3]));
#pragma unroll
        for (int off = 32; off > 0; off >>= 1) m = fmaxf(m, __shfl_xor(m, off, 64));
        float s = 0.f, pp = 0.f;
#pragma unroll
        for (int j = 0; j < 4; j++) {
            int k = lane + 64 * j;
            float e = (k < NS) ? __expf(lg[j] - m) : 0.f;
            s += e;
            if (k == pick) pp = e;
        }
#pragma unroll
        for (int off = 32; off > 0; off >>= 1) {
            s += __shfl_xor(s, off, 64);
            pp += __shfl_xor(pp, off, 64);
        }
        p[lvl] = pp / s;
    }
    if (lane == 0) out[row] = p[0] * p[1];
}

// ---------------------------------------------------------------------------
extern "C" void kernel_launch(void* const* d_in, const int* in_sizes, int n_in,
                              void* d_out, int out_size, void* d_ws, size_t ws_size,
                              hipStream_t stream) {
    const float* inputs   = (const float*)d_in[0];
    const int*   labels   = (const int*)d_in[1];
    const float* W_top    = (const float*)d_in[2];
    const float* b_top    = (const float*)d_in[3];
    const float* W_bottom = (const float*)d_in[4];
    const float* b_bottom = (const float*)d_in[5];
    float* out = (float*)d_out;

    // ws layout: bucket[NCLS*CAP] | cnt[NCLS] | tws[BATCH*LSTRIDE] | bws[...]
    int* bucket = (int*)d_ws;
    int* cnt    = bucket + NCLS * CAP;
    float* tws  = (float*)(cnt + NCLS);
    float* bws  = tws + (size_t)BATCH * LSTRIDE;

    hs_bucket<<<1, 256, 0, stream>>>(labels, bucket, cnt);
    hs_tlogits<<<BATCH / 8, 1024, 0, stream>>>(inputs, W_top, tws);
    hs_blogits<<<NCLS * 4, 1024, 0, stream>>>(inputs, W_bottom, bucket, cnt, bws);
    hs_finish<<<BATCH / 4, 256, 0, stream>>>(tws, bws, labels, b_top, b_bottom, out);
}